// Round 7
// baseline (253.287 us; speedup 1.0000x reference)
//
#include <hip/hip_runtime.h>
#include <hip/hip_bf16.h>
#include <cmath>

#define NN 8192
#define FIN 512
#define FD 64
#define IT 16            // rows per k_attn block
#define JC 128           // j-chunk (4 waves x 32 k)
#define NCH (NN / JC)    // 64 chunks
#define NWORDS (NN * (NN / 32))   // 2M bitmask words

typedef __attribute__((ext_vector_type(4))) float f32x4;
typedef __attribute__((ext_vector_type(4))) int   i32x4;
typedef __attribute__((ext_vector_type(8))) short s16x8;

static __device__ __forceinline__ s16x8 as_s16x8(i32x4 v) {
    s16x8 r; __builtin_memcpy(&r, &v, 16); return r;
}
static __device__ __forceinline__ short bf16bits(float f) {
    __hip_bfloat16 h = __float2bfloat16(f);
    short s; __builtin_memcpy(&s, &h, 2); return s;
}

// ---------------- kernel 0: adj (256MB int32) -> bitmask (8MB) ---------------
// Wave-cooperative: per round a wave reads 512 contiguous ints via 8 coalesced
// dword loads (lane l: fb + 64*i + l), 8 ballots give 8 uniform u64 masks in
// column-bit order, lanes 0..15 store 16 words (64B contiguous).
__global__ __launch_bounds__(256) void k_compress(const int* __restrict__ adj,
        unsigned* __restrict__ bm)
{
    const int t = threadIdx.x;
    const int l = t & 63;
    const int wv = t >> 6;
    const size_t fb0 = (size_t)blockIdx.x * 65536 + (size_t)wv * 16384;

    for (int r = 0; r < 32; ++r) {
        const size_t fb = fb0 + (size_t)r * 512;
        const int* p = adj + fb + l;
        const unsigned long long m0 = __ballot(__builtin_nontemporal_load(p +   0) > 0);
        const unsigned long long m1 = __ballot(__builtin_nontemporal_load(p +  64) > 0);
        const unsigned long long m2 = __ballot(__builtin_nontemporal_load(p + 128) > 0);
        const unsigned long long m3 = __ballot(__builtin_nontemporal_load(p + 192) > 0);
        const unsigned long long m4 = __ballot(__builtin_nontemporal_load(p + 256) > 0);
        const unsigned long long m5 = __ballot(__builtin_nontemporal_load(p + 320) > 0);
        const unsigned long long m6 = __ballot(__builtin_nontemporal_load(p + 384) > 0);
        const unsigned long long m7 = __ballot(__builtin_nontemporal_load(p + 448) > 0);
        if (l < 16) {
            const int i = l >> 1;
            const unsigned long long mm =
                (i < 4) ? ((i < 2) ? (i == 0 ? m0 : m1) : (i == 2 ? m2 : m3))
                        : ((i < 6) ? (i == 4 ? m4 : m5) : (i == 6 ? m6 : m7));
            const unsigned v = (l & 1) ? (unsigned)(mm >> 32) : (unsigned)mm;
            bm[fb / 32 + l] = v;
        }
    }
}

// ---------------- kernel 1: h = x@W (bf16, transposed) ; src/dst -------------
__global__ __launch_bounds__(256) void k_proj(const float* __restrict__ x,
        const float* __restrict__ W, const float* __restrict__ a,
        short* __restrict__ hT, float* __restrict__ src, float* __restrict__ dst)
{
    __shared__ short tl[32][64];
    const int t = threadIdx.x, lane = t & 63, wv = t >> 6;
    const int row0 = blockIdx.x * 32;
    const int r0 = wv * 8;
    const float a1 = a[lane], a2 = a[FD + lane];

    float acc[8] = {0.f,0.f,0.f,0.f,0.f,0.f,0.f,0.f};
    for (int k0 = 0; k0 < FIN; k0 += 4) {
        const float w0 = W[(k0+0)*FD + lane];
        const float w1 = W[(k0+1)*FD + lane];
        const float w2 = W[(k0+2)*FD + lane];
        const float w3 = W[(k0+3)*FD + lane];
        #pragma unroll
        for (int r = 0; r < 8; ++r) {
            const float4 xv = *reinterpret_cast<const float4*>(&x[(size_t)(row0+r0+r)*FIN + k0]);
            acc[r] = fmaf(xv.x, w0, fmaf(xv.y, w1, fmaf(xv.z, w2, fmaf(xv.w, w3, acc[r]))));
        }
    }
    #pragma unroll
    for (int r = 0; r < 8; ++r) {
        tl[r0 + r][lane] = bf16bits(acc[r]);
        float p1 = acc[r] * a1, p2 = acc[r] * a2;
        #pragma unroll
        for (int s = 32; s > 0; s >>= 1) { p1 += __shfl_xor(p1, s); p2 += __shfl_xor(p2, s); }
        if (lane == 0) { src[row0 + r0 + r] = p1; dst[row0 + r0 + r] = p2; }
    }
    __syncthreads();
    // transpose out: thread t -> feature f = t>>2, rows (t&3)*8 .. +8
    const int f = t >> 2, rr = (t & 3) * 8;
    alignas(16) short tmp[8];
    #pragma unroll
    for (int k = 0; k < 8; ++k) tmp[k] = tl[rr + k][f];
    *reinterpret_cast<int4*>(&hT[(size_t)f * NN + row0 + rr]) = *reinterpret_cast<int4*>(tmp);
}

// ---------------- kernel 2: barrier-free fused gen + MFMA PV -----------------
// Identical to round 6 EXCEPT: #pragma unroll 1 on the main loop. Theory: LLVM
// was fully unrolling the 32-trip loop, overlapping ~dozens of LOADSET live
// ranges, blowing the 128-VGPR cap (launch_bounds 256,2) -> scratch spills at
// HBM latency every chunk = the stable ~120us plateau.
__global__ __launch_bounds__(256, 2) void k_attn(const unsigned* __restrict__ bm,
        const short* __restrict__ hT, const float* __restrict__ src,
        const float* __restrict__ dst, float* __restrict__ out)
{
    __shared__ float cred[4][16][68];   // [wave][row][f] (+4 pad: no write conflicts)
    __shared__ float dred[4][16];

    const int t = threadIdx.x;
    const int i0 = blockIdx.x * IT;
    const int w   = t >> 6;          // wave = k-slice
    const int l   = t & 63;
    const int row = l & 15;          // A row / C col
    const int kg  = l >> 4;          // k-group
    const int kb  = kg * 8;          // bit base within the 32-col mask word
    const int cb  = w * 32 + kb;     // column base within chunk

    const float sv = src[i0 + row];
    float dsum = 0.f;
    f32x4 acc0 = {0.f,0.f,0.f,0.f}, acc1 = {0.f,0.f,0.f,0.f};
    f32x4 acc2 = {0.f,0.f,0.f,0.f}, acc3 = {0.f,0.f,0.f,0.f};

    const unsigned* mp  = bm + (size_t)(i0 + row) * (NN / 32) + w;   // +4 per chunk
    const f32x4*  dp  = (const f32x4*)(dst + cb);
    const i32x4*  hp0 = (const i32x4*)(hT + (size_t)(0*16 + row) * NN + cb);
    const i32x4*  hp1 = (const i32x4*)(hT + (size_t)(1*16 + row) * NN + cb);
    const i32x4*  hp2 = (const i32x4*)(hT + (size_t)(2*16 + row) * NN + cb);
    const i32x4*  hp3 = (const i32x4*)(hT + (size_t)(3*16 + row) * NN + cb);

#define GEN(M,D0,D1,PK) do { \
    const float di[8] = {(D0).x,(D0).y,(D0).z,(D0).w,(D1).x,(D1).y,(D1).z,(D1).w}; \
    const unsigned Ms = (M) >> kb; \
    _Pragma("unroll") \
    for (int e = 0; e < 8; ++e) { \
        float ev = sv + di[e]; \
        ev = fmaxf(ev, 0.2f * ev); \
        float wv_ = ((Ms >> e) & 1u) ? __expf(ev) : 0.f; \
        dsum += wv_; \
        (PK)[e] = bf16bits(wv_); \
    } \
} while (0)

#define LOADSET(S, guard) do { if (guard) { \
    m##S = mp[0]; \
    d##S##0 = dp[0]; d##S##1 = dp[1]; \
    h##S##0 = hp0[0]; h##S##1 = hp1[0]; h##S##2 = hp2[0]; h##S##3 = hp3[0]; \
    mp += 4; dp += 32; hp0 += 16; hp1 += 16; hp2 += 16; hp3 += 16; } \
} while (0)

#define MM(PK,H0,H1,H2,H3) do { \
    acc0 = __builtin_amdgcn_mfma_f32_16x16x32_bf16((PK), as_s16x8(H0), acc0, 0, 0, 0); \
    acc1 = __builtin_amdgcn_mfma_f32_16x16x32_bf16((PK), as_s16x8(H1), acc1, 0, 0, 0); \
    acc2 = __builtin_amdgcn_mfma_f32_16x16x32_bf16((PK), as_s16x8(H2), acc2, 0, 0, 0); \
    acc3 = __builtin_amdgcn_mfma_f32_16x16x32_bf16((PK), as_s16x8(H3), acc3, 0, 0, 0); \
} while (0)

    // prefetch chunk 0 into set A
    unsigned mA = mp[0];
    f32x4 dA0 = dp[0], dA1 = dp[1];
    i32x4 hA0 = hp0[0], hA1 = hp1[0], hA2 = hp2[0], hA3 = hp3[0];
    mp += 4; dp += 32; hp0 += 16; hp1 += 16; hp2 += 16; hp3 += 16;
    unsigned mB; f32x4 dB0, dB1; i32x4 hB0, hB1, hB2, hB3;
    s16x8 pkA, pkB;

    #pragma unroll 1
    for (int c = 0; c < NCH; c += 2) {
        LOADSET(B, (c + 1) < NCH);
        GEN(mA, dA0, dA1, pkA);
        MM(pkA, hA0, hA1, hA2, hA3);
        LOADSET(A, (c + 2) < NCH);
        GEN(mB, dB0, dB1, pkB);
        MM(pkB, hB0, hB1, hB2, hB3);
    }

#undef GEN
#undef LOADSET
#undef MM

    // denominator: sum the 4 k-groups of each row within the wave
    float d2 = dsum;
    d2 += __shfl_xor(d2, 16);
    d2 += __shfl_xor(d2, 32);
    if (kg == 0) dred[w][row] = d2;

    // C partials -> LDS
    #pragma unroll
    for (int j = 0; j < 4; ++j) {
        cred[w][kg*4 + j][0*16 + row] = acc0[j];
        cred[w][kg*4 + j][1*16 + row] = acc1[j];
        cred[w][kg*4 + j][2*16 + row] = acc2[j];
        cred[w][kg*4 + j][3*16 + row] = acc3[j];
    }
    __syncthreads();

    // combine across waves (k-slices), divide, ELU, store. thread t -> row t>>4,
    // f = (t&15)*4 .. +4  (coalesced float4 store)
    const int r  = t >> 4;
    const int f0 = (t & 15) * 4;
    const float den = dred[0][r] + dred[1][r] + dred[2][r] + dred[3][r];
    float4 o;
    float* op = (float*)&o;
    #pragma unroll
    for (int e = 0; e < 4; ++e) {
        float v = cred[0][r][f0+e] + cred[1][r][f0+e] + cred[2][r][f0+e] + cred[3][r][f0+e];
        v /= den;
        op[e] = (v > 0.f) ? v : expm1f(v);
    }
    *reinterpret_cast<float4*>(&out[(size_t)(i0 + r) * FD + f0]) = o;
}

extern "C" void kernel_launch(void* const* d_in, const int* in_sizes, int n_in,
                              void* d_out, int out_size, void* d_ws, size_t ws_size,
                              hipStream_t stream) {
    const float* x   = (const float*)d_in[0];
    const int*   adj = (const int*)d_in[1];
    const float* W   = (const float*)d_in[2];
    const float* a   = (const float*)d_in[3];
    float* out = (float*)d_out;

    unsigned* bmw = (unsigned*)d_ws;                         // 2M words = 8 MB
    short* hT  = (short*)(bmw + NWORDS);                     // 64 x 8192 bf16 = 1 MB
    float* src = (float*)((char*)hT + (size_t)FD * NN * 2);  // 8192 f32
    float* dst = src + NN;                                   // 8192 f32

    k_compress<<<1024, 256, 0, stream>>>(adj, bmw);
    k_proj<<<NN / 32, 256, 0, stream>>>(x, W, a, hT, src, dst);
    // Launched TWICE this round (deterministic: identical work/output) so
    // k_attn's true per-dispatch cost is recoverable from the total:
    // attn_us = (total - compress - proj) / 2.
    k_attn<<<NN / IT, 256, 0, stream>>>(bmw, hT, src, dst, out);
    k_attn<<<NN / IT, 256, 0, stream>>>(bmw, hT, src, dst, out);
}

// Round 8
// 236.126 us; speedup vs baseline: 1.0727x; 1.0727x over previous
//
#include <hip/hip_runtime.h>
#include <hip/hip_bf16.h>
#include <cmath>

#define NN 8192
#define FIN 512
#define FD 64
#define IT 32            // rows per k_attn block
#define JCW 256          // j-chunk (8 waves x 32 k)
#define NCH (NN / JCW)   // 32 chunks
#define NWORDS (NN * (NN / 32))   // 2M bitmask words
#define REP 3            // diagnostic repeat (identical output per rep)

typedef __attribute__((ext_vector_type(4))) float f32x4;
typedef __attribute__((ext_vector_type(4))) int   i32x4;
typedef __attribute__((ext_vector_type(8))) short s16x8;

static __device__ __forceinline__ s16x8 as_s16x8(i32x4 v) {
    s16x8 r; __builtin_memcpy(&r, &v, 16); return r;
}
static __device__ __forceinline__ short bf16bits(float f) {
    __hip_bfloat16 h = __float2bfloat16(f);
    short s; __builtin_memcpy(&s, &h, 2); return s;
}

// ---------------- kernel 0: adj (256MB int32) -> bitmask (8MB) ---------------
__global__ __launch_bounds__(256) void k_compress(const int* __restrict__ adj,
        unsigned* __restrict__ bm)
{
    const int t = threadIdx.x;
    const int l = t & 63;
    const int wv = t >> 6;
    const size_t fb0 = (size_t)blockIdx.x * 65536 + (size_t)wv * 16384;

    for (int r = 0; r < 32; ++r) {
        const size_t fb = fb0 + (size_t)r * 512;
        const int* p = adj + fb + l;
        const unsigned long long m0 = __ballot(__builtin_nontemporal_load(p +   0) > 0);
        const unsigned long long m1 = __ballot(__builtin_nontemporal_load(p +  64) > 0);
        const unsigned long long m2 = __ballot(__builtin_nontemporal_load(p + 128) > 0);
        const unsigned long long m3 = __ballot(__builtin_nontemporal_load(p + 192) > 0);
        const unsigned long long m4 = __ballot(__builtin_nontemporal_load(p + 256) > 0);
        const unsigned long long m5 = __ballot(__builtin_nontemporal_load(p + 320) > 0);
        const unsigned long long m6 = __ballot(__builtin_nontemporal_load(p + 384) > 0);
        const unsigned long long m7 = __ballot(__builtin_nontemporal_load(p + 448) > 0);
        if (l < 16) {
            const int i = l >> 1;
            const unsigned long long mm =
                (i < 4) ? ((i < 2) ? (i == 0 ? m0 : m1) : (i == 2 ? m2 : m3))
                        : ((i < 6) ? (i == 4 ? m4 : m5) : (i == 6 ? m6 : m7));
            const unsigned v = (l & 1) ? (unsigned)(mm >> 32) : (unsigned)mm;
            bm[fb / 32 + l] = v;
        }
    }
}

// ---------------- kernel 1: h = x@W (bf16, transposed) ; src/dst -------------
__global__ __launch_bounds__(256) void k_proj(const float* __restrict__ x,
        const float* __restrict__ W, const float* __restrict__ a,
        short* __restrict__ hT, float* __restrict__ src, float* __restrict__ dst)
{
    __shared__ short tl[32][64];
    const int t = threadIdx.x, lane = t & 63, wv = t >> 6;
    const int row0 = blockIdx.x * 32;
    const int r0 = wv * 8;
    const float a1 = a[lane], a2 = a[FD + lane];

    float acc[8] = {0.f,0.f,0.f,0.f,0.f,0.f,0.f,0.f};
    for (int k0 = 0; k0 < FIN; k0 += 4) {
        const float w0 = W[(k0+0)*FD + lane];
        const float w1 = W[(k0+1)*FD + lane];
        const float w2 = W[(k0+2)*FD + lane];
        const float w3 = W[(k0+3)*FD + lane];
        #pragma unroll
        for (int r = 0; r < 8; ++r) {
            const float4 xv = *reinterpret_cast<const float4*>(&x[(size_t)(row0+r0+r)*FIN + k0]);
            acc[r] = fmaf(xv.x, w0, fmaf(xv.y, w1, fmaf(xv.z, w2, fmaf(xv.w, w3, acc[r]))));
        }
    }
    #pragma unroll
    for (int r = 0; r < 8; ++r) {
        tl[r0 + r][lane] = bf16bits(acc[r]);
        float p1 = acc[r] * a1, p2 = acc[r] * a2;
        #pragma unroll
        for (int s = 32; s > 0; s >>= 1) { p1 += __shfl_xor(p1, s); p2 += __shfl_xor(p2, s); }
        if (lane == 0) { src[row0 + r0 + r] = p1; dst[row0 + r0 + r] = p2; }
    }
    __syncthreads();
    const int f = t >> 2, rr = (t & 3) * 8;
    alignas(16) short tmp[8];
    #pragma unroll
    for (int k = 0; k < 8; ++k) tmp[k] = tl[rr + k][f];
    *reinterpret_cast<int4*>(&hT[(size_t)f * NN + row0 + rr]) = *reinterpret_cast<int4*>(tmp);
}

// ---------------- kernel 2: barrier-free fused gen + MFMA PV -----------------
// 256 blocks x 512 thr (8 waves = 8 k-slices of a 256-wide j-chunk). Block =
// 32 rows (2 i-tiles per wave) -> each hT B-frag feeds 2 MFMAs, halving the
// scattered hT traffic vs IT=16. GEN output feeds MFMA directly from regs;
// no main-loop barriers. REP x identical passes for counter visibility.
__global__ __launch_bounds__(512, 2) void k_attn(const unsigned* __restrict__ bm,
        const short* __restrict__ hT, const float* __restrict__ src,
        const float* __restrict__ dst, float* __restrict__ out)
{
    __shared__ float cred[8][32][68];   // [wave][row][f] (+4 pad)
    __shared__ float dred[8][32];

    const int t = threadIdx.x;
    const int i0 = blockIdx.x * IT;
    const int w   = t >> 6;          // wave = k-slice 0..7
    const int l   = t & 63;
    const int row = l & 15;          // A row (i-tile-local) / C col
    const int kg  = l >> 4;          // k-group
    const int kb  = kg * 8;          // bit base within the 32-col mask word
    const int cb  = w * 32 + kb;     // column base within 256-wide chunk

    const float sv0 = src[i0 + row];
    const float sv1 = src[i0 + 16 + row];

#define GEN(M,D0,D1,SV,DS,PK) do { \
    const float di[8] = {(D0).x,(D0).y,(D0).z,(D0).w,(D1).x,(D1).y,(D1).z,(D1).w}; \
    const unsigned Ms = (M) >> kb; \
    _Pragma("unroll") \
    for (int e = 0; e < 8; ++e) { \
        float ev = (SV) + di[e]; \
        ev = fmaxf(ev, 0.2f * ev); \
        float wv_ = ((Ms >> e) & 1u) ? __expf(ev) : 0.f; \
        (DS) += wv_; \
        (PK)[e] = bf16bits(wv_); \
    } \
} while (0)

#define LOADSET(S, guard) do { if (guard) { \
    m##S##0 = mp0[0]; m##S##1 = mp1[0]; \
    d##S##0 = dp[0];  d##S##1 = dp[1]; \
    h##S##0 = hp0[0]; h##S##1 = hp1[0]; h##S##2 = hp2[0]; h##S##3 = hp3[0]; \
    mp0 += 8; mp1 += 8; dp += 64; hp0 += 32; hp1 += 32; hp2 += 32; hp3 += 32; } \
} while (0)

#define MM8(PK0,PK1,H0,H1,H2,H3) do { \
    q00 = __builtin_amdgcn_mfma_f32_16x16x32_bf16((PK0), as_s16x8(H0), q00, 0, 0, 0); \
    q01 = __builtin_amdgcn_mfma_f32_16x16x32_bf16((PK0), as_s16x8(H1), q01, 0, 0, 0); \
    q02 = __builtin_amdgcn_mfma_f32_16x16x32_bf16((PK0), as_s16x8(H2), q02, 0, 0, 0); \
    q03 = __builtin_amdgcn_mfma_f32_16x16x32_bf16((PK0), as_s16x8(H3), q03, 0, 0, 0); \
    q10 = __builtin_amdgcn_mfma_f32_16x16x32_bf16((PK1), as_s16x8(H0), q10, 0, 0, 0); \
    q11 = __builtin_amdgcn_mfma_f32_16x16x32_bf16((PK1), as_s16x8(H1), q11, 0, 0, 0); \
    q12 = __builtin_amdgcn_mfma_f32_16x16x32_bf16((PK1), as_s16x8(H2), q12, 0, 0, 0); \
    q13 = __builtin_amdgcn_mfma_f32_16x16x32_bf16((PK1), as_s16x8(H3), q13, 0, 0, 0); \
} while (0)

    #pragma unroll 1
    for (int rep = 0; rep < REP; ++rep) {
        float dsum0 = 0.f, dsum1 = 0.f;
        f32x4 q00 = {0.f,0.f,0.f,0.f}, q01 = {0.f,0.f,0.f,0.f};
        f32x4 q02 = {0.f,0.f,0.f,0.f}, q03 = {0.f,0.f,0.f,0.f};
        f32x4 q10 = {0.f,0.f,0.f,0.f}, q11 = {0.f,0.f,0.f,0.f};
        f32x4 q12 = {0.f,0.f,0.f,0.f}, q13 = {0.f,0.f,0.f,0.f};

        const unsigned* mp0 = bm + (size_t)(i0 + row) * (NN / 32) + w;
        const unsigned* mp1 = bm + (size_t)(i0 + 16 + row) * (NN / 32) + w;
        const f32x4*  dp  = (const f32x4*)(dst + cb);
        const i32x4*  hp0 = (const i32x4*)(hT + (size_t)(0*16 + row) * NN + cb);
        const i32x4*  hp1 = (const i32x4*)(hT + (size_t)(1*16 + row) * NN + cb);
        const i32x4*  hp2 = (const i32x4*)(hT + (size_t)(2*16 + row) * NN + cb);
        const i32x4*  hp3 = (const i32x4*)(hT + (size_t)(3*16 + row) * NN + cb);

        // prefetch chunk 0 into set A
        unsigned mA0 = mp0[0], mA1 = mp1[0];
        f32x4 dA0 = dp[0], dA1 = dp[1];
        i32x4 hA0 = hp0[0], hA1 = hp1[0], hA2 = hp2[0], hA3 = hp3[0];
        mp0 += 8; mp1 += 8; dp += 64; hp0 += 32; hp1 += 32; hp2 += 32; hp3 += 32;
        unsigned mB0, mB1; f32x4 dB0, dB1; i32x4 hB0, hB1, hB2, hB3;
        s16x8 pkA0, pkA1, pkB0, pkB1;

        #pragma unroll 1
        for (int c = 0; c < NCH; c += 2) {
            LOADSET(B, (c + 1) < NCH);
            GEN(mA0, dA0, dA1, sv0, dsum0, pkA0);
            GEN(mA1, dA0, dA1, sv1, dsum1, pkA1);
            MM8(pkA0, pkA1, hA0, hA1, hA2, hA3);
            LOADSET(A, (c + 2) < NCH);
            GEN(mB0, dB0, dB1, sv0, dsum0, pkB0);
            GEN(mB1, dB0, dB1, sv1, dsum1, pkB1);
            MM8(pkB0, pkB1, hB0, hB1, hB2, hB3);
        }

        // denominators: reduce the 4 k-groups within the wave
        float d2 = dsum0;
        d2 += __shfl_xor(d2, 16); d2 += __shfl_xor(d2, 32);
        if (kg == 0) dred[w][row] = d2;
        float d3 = dsum1;
        d3 += __shfl_xor(d3, 16); d3 += __shfl_xor(d3, 32);
        if (kg == 0) dred[w][16 + row] = d3;

        #pragma unroll
        for (int j = 0; j < 4; ++j) {
            cred[w][kg*4 + j][0*16 + row] = q00[j];
            cred[w][kg*4 + j][1*16 + row] = q01[j];
            cred[w][kg*4 + j][2*16 + row] = q02[j];
            cred[w][kg*4 + j][3*16 + row] = q03[j];
            cred[w][16 + kg*4 + j][0*16 + row] = q10[j];
            cred[w][16 + kg*4 + j][1*16 + row] = q11[j];
            cred[w][16 + kg*4 + j][2*16 + row] = q12[j];
            cred[w][16 + kg*4 + j][3*16 + row] = q13[j];
        }
        __syncthreads();

        // combine across 8 waves, divide, ELU, store. thread t -> row t>>4,
        // f = (t&15)*4 (coalesced float4 store)
        const int r  = t >> 4;
        const int f0 = (t & 15) * 4;
        float den = 0.f;
        #pragma unroll
        for (int ww = 0; ww < 8; ++ww) den += dred[ww][r];
        float4 o;
        float* op = (float*)&o;
        #pragma unroll
        for (int e = 0; e < 4; ++e) {
            float v = 0.f;
            #pragma unroll
            for (int ww = 0; ww < 8; ++ww) v += cred[ww][r][f0 + e];
            v /= den;
            op[e] = (v > 0.f) ? v : expm1f(v);
        }
        *reinterpret_cast<float4*>(&out[(size_t)(i0 + r) * FD + f0]) = o;
        __syncthreads();   // protect cred/dred before next rep overwrites
    }

#undef GEN
#undef LOADSET
#undef MM8
}

extern "C" void kernel_launch(void* const* d_in, const int* in_sizes, int n_in,
                              void* d_out, int out_size, void* d_ws, size_t ws_size,
                              hipStream_t stream) {
    const float* x   = (const float*)d_in[0];
    const int*   adj = (const int*)d_in[1];
    const float* W   = (const float*)d_in[2];
    const float* a   = (const float*)d_in[3];
    float* out = (float*)d_out;

    unsigned* bmw = (unsigned*)d_ws;                         // 2M words = 8 MB
    short* hT  = (short*)(bmw + NWORDS);                     // 64 x 8192 bf16 = 1 MB
    float* src = (float*)((char*)hT + (size_t)FD * NN * 2);  // 8192 f32
    float* dst = src + NN;                                   // 8192 f32

    k_compress<<<1024, 256, 0, stream>>>(adj, bmw);
    k_proj<<<NN / 32, 256, 0, stream>>>(x, W, a, hT, src, dst);
    k_attn<<<NN / IT, 512, 0, stream>>>(bmw, hT, src, dst, out);
}

// Round 9
// 146.949 us; speedup vs baseline: 1.7236x; 1.6069x over previous
//
#include <hip/hip_runtime.h>
#include <hip/hip_bf16.h>
#include <cmath>

#define NN 8192
#define FIN 512
#define FD 64
#define IT 32            // rows per k_attn block
#define JCW 256          // j-chunk (8 waves x 32 k)
#define JSPLIT 2         // j-range split (occupancy: 512 blocks = 2/CU)
#define JRANGE (NN / JSPLIT)      // 4096
#define NCHS (JRANGE / JCW)       // 16 chunks
#define NWORDS (NN * (NN / 32))   // 2M bitmask words

typedef __attribute__((ext_vector_type(4))) float f32x4;
typedef __attribute__((ext_vector_type(4))) int   i32x4;
typedef __attribute__((ext_vector_type(8))) short s16x8;

static __device__ __forceinline__ s16x8 as_s16x8(i32x4 v) {
    s16x8 r; __builtin_memcpy(&r, &v, 16); return r;
}
static __device__ __forceinline__ short bf16bits(float f) {
    __hip_bfloat16 h = __float2bfloat16(f);
    short s; __builtin_memcpy(&s, &h, 2); return s;
}

// ---------------- kernel 0: adj (256MB int32) -> bitmask (8MB) ---------------
__global__ __launch_bounds__(256) void k_compress(const int* __restrict__ adj,
        unsigned* __restrict__ bm)
{
    const int t = threadIdx.x;
    const int l = t & 63;
    const int wv = t >> 6;
    const size_t fb0 = (size_t)blockIdx.x * 65536 + (size_t)wv * 16384;

    for (int r = 0; r < 32; ++r) {
        const size_t fb = fb0 + (size_t)r * 512;
        const int* p = adj + fb + l;
        const unsigned long long m0 = __ballot(__builtin_nontemporal_load(p +   0) > 0);
        const unsigned long long m1 = __ballot(__builtin_nontemporal_load(p +  64) > 0);
        const unsigned long long m2 = __ballot(__builtin_nontemporal_load(p + 128) > 0);
        const unsigned long long m3 = __ballot(__builtin_nontemporal_load(p + 192) > 0);
        const unsigned long long m4 = __ballot(__builtin_nontemporal_load(p + 256) > 0);
        const unsigned long long m5 = __ballot(__builtin_nontemporal_load(p + 320) > 0);
        const unsigned long long m6 = __ballot(__builtin_nontemporal_load(p + 384) > 0);
        const unsigned long long m7 = __ballot(__builtin_nontemporal_load(p + 448) > 0);
        if (l < 16) {
            const int i = l >> 1;
            const unsigned long long mm =
                (i < 4) ? ((i < 2) ? (i == 0 ? m0 : m1) : (i == 2 ? m2 : m3))
                        : ((i < 6) ? (i == 4 ? m4 : m5) : (i == 6 ? m6 : m7));
            const unsigned v = (l & 1) ? (unsigned)(mm >> 32) : (unsigned)mm;
            bm[fb / 32 + l] = v;
        }
    }
}

// ---------------- kernel 1: h = x@W (bf16, transposed) ; src/dst -------------
__global__ __launch_bounds__(256) void k_proj(const float* __restrict__ x,
        const float* __restrict__ W, const float* __restrict__ a,
        short* __restrict__ hT, float* __restrict__ src, float* __restrict__ dst)
{
    __shared__ short tl[32][64];
    const int t = threadIdx.x, lane = t & 63, wv = t >> 6;
    const int row0 = blockIdx.x * 32;
    const int r0 = wv * 8;
    const float a1 = a[lane], a2 = a[FD + lane];

    float acc[8] = {0.f,0.f,0.f,0.f,0.f,0.f,0.f,0.f};
    for (int k0 = 0; k0 < FIN; k0 += 4) {
        const float w0 = W[(k0+0)*FD + lane];
        const float w1 = W[(k0+1)*FD + lane];
        const float w2 = W[(k0+2)*FD + lane];
        const float w3 = W[(k0+3)*FD + lane];
        #pragma unroll
        for (int r = 0; r < 8; ++r) {
            const float4 xv = *reinterpret_cast<const float4*>(&x[(size_t)(row0+r0+r)*FIN + k0]);
            acc[r] = fmaf(xv.x, w0, fmaf(xv.y, w1, fmaf(xv.z, w2, fmaf(xv.w, w3, acc[r]))));
        }
    }
    #pragma unroll
    for (int r = 0; r < 8; ++r) {
        tl[r0 + r][lane] = bf16bits(acc[r]);
        float p1 = acc[r] * a1, p2 = acc[r] * a2;
        #pragma unroll
        for (int s = 32; s > 0; s >>= 1) { p1 += __shfl_xor(p1, s); p2 += __shfl_xor(p2, s); }
        if (lane == 0) { src[row0 + r0 + r] = p1; dst[row0 + r0 + r] = p2; }
    }
    __syncthreads();
    const int f = t >> 2, rr = (t & 3) * 8;
    alignas(16) short tmp[8];
    #pragma unroll
    for (int k = 0; k < 8; ++k) tmp[k] = tl[rr + k][f];
    *reinterpret_cast<int4*>(&hT[(size_t)f * NN + row0 + rr]) = *reinterpret_cast<int4*>(tmp);
}

// ---------------- kernel 2: barrier-free fused gen + MFMA PV (partials) ------
// 512 blocks x 512 thr: block (ib,jb) = 32 rows x half the j-range -> 2
// blocks/CU, 4 waves/SIMD (the round-8 fix: grid was 1 block/CU, 2 waves/SIMD,
// latency exposed). Partial acc/den written to ws; k_merge combines.
__global__ __launch_bounds__(512, 2) void k_attn(const unsigned* __restrict__ bm,
        const short* __restrict__ hT, const float* __restrict__ src,
        const float* __restrict__ dst, float* __restrict__ pacc,
        float* __restrict__ pden)
{
    __shared__ float cred[8][32][68];   // [wave][row][f] (+4 pad)
    __shared__ float dred[8][32];

    const int t = threadIdx.x;
    const int jb = blockIdx.x & (JSPLIT - 1);
    const int i0 = (blockIdx.x >> 1) * IT;
    const int jbase = jb * JRANGE;
    const int w   = t >> 6;          // wave = k-slice 0..7
    const int l   = t & 63;
    const int row = l & 15;          // A row (i-tile-local) / C col
    const int kg  = l >> 4;          // k-group
    const int kb  = kg * 8;          // bit base within the 32-col mask word
    const int cb  = w * 32 + kb;     // column base within 256-wide chunk

    const float sv0 = src[i0 + row];
    const float sv1 = src[i0 + 16 + row];

    float dsum0 = 0.f, dsum1 = 0.f;
    f32x4 q00 = {0.f,0.f,0.f,0.f}, q01 = {0.f,0.f,0.f,0.f};
    f32x4 q02 = {0.f,0.f,0.f,0.f}, q03 = {0.f,0.f,0.f,0.f};
    f32x4 q10 = {0.f,0.f,0.f,0.f}, q11 = {0.f,0.f,0.f,0.f};
    f32x4 q12 = {0.f,0.f,0.f,0.f}, q13 = {0.f,0.f,0.f,0.f};

    const unsigned* mp0 = bm + (size_t)(i0 + row) * (NN / 32) + jbase / 32 + w;
    const unsigned* mp1 = bm + (size_t)(i0 + 16 + row) * (NN / 32) + jbase / 32 + w;
    const f32x4*  dp  = (const f32x4*)(dst + jbase + cb);
    const i32x4*  hp0 = (const i32x4*)(hT + (size_t)(0*16 + row) * NN + jbase + cb);
    const i32x4*  hp1 = (const i32x4*)(hT + (size_t)(1*16 + row) * NN + jbase + cb);
    const i32x4*  hp2 = (const i32x4*)(hT + (size_t)(2*16 + row) * NN + jbase + cb);
    const i32x4*  hp3 = (const i32x4*)(hT + (size_t)(3*16 + row) * NN + jbase + cb);

#define GEN(M,D0,D1,SV,DS,PK) do { \
    const float di[8] = {(D0).x,(D0).y,(D0).z,(D0).w,(D1).x,(D1).y,(D1).z,(D1).w}; \
    const unsigned Ms = (M) >> kb; \
    _Pragma("unroll") \
    for (int e = 0; e < 8; ++e) { \
        float ev = (SV) + di[e]; \
        ev = fmaxf(ev, 0.2f * ev); \
        float wv_ = ((Ms >> e) & 1u) ? __expf(ev) : 0.f; \
        (DS) += wv_; \
        (PK)[e] = bf16bits(wv_); \
    } \
} while (0)

#define LOADSET(S, guard) do { if (guard) { \
    m##S##0 = mp0[0]; m##S##1 = mp1[0]; \
    d##S##0 = dp[0];  d##S##1 = dp[1]; \
    h##S##0 = hp0[0]; h##S##1 = hp1[0]; h##S##2 = hp2[0]; h##S##3 = hp3[0]; \
    mp0 += 8; mp1 += 8; dp += 64; hp0 += 32; hp1 += 32; hp2 += 32; hp3 += 32; } \
} while (0)

#define MM8(PK0,PK1,H0,H1,H2,H3) do { \
    q00 = __builtin_amdgcn_mfma_f32_16x16x32_bf16((PK0), as_s16x8(H0), q00, 0, 0, 0); \
    q01 = __builtin_amdgcn_mfma_f32_16x16x32_bf16((PK0), as_s16x8(H1), q01, 0, 0, 0); \
    q02 = __builtin_amdgcn_mfma_f32_16x16x32_bf16((PK0), as_s16x8(H2), q02, 0, 0, 0); \
    q03 = __builtin_amdgcn_mfma_f32_16x16x32_bf16((PK0), as_s16x8(H3), q03, 0, 0, 0); \
    q10 = __builtin_amdgcn_mfma_f32_16x16x32_bf16((PK1), as_s16x8(H0), q10, 0, 0, 0); \
    q11 = __builtin_amdgcn_mfma_f32_16x16x32_bf16((PK1), as_s16x8(H1), q11, 0, 0, 0); \
    q12 = __builtin_amdgcn_mfma_f32_16x16x32_bf16((PK1), as_s16x8(H2), q12, 0, 0, 0); \
    q13 = __builtin_amdgcn_mfma_f32_16x16x32_bf16((PK1), as_s16x8(H3), q13, 0, 0, 0); \
} while (0)

    // prefetch chunk 0 into set A
    unsigned mA0 = mp0[0], mA1 = mp1[0];
    f32x4 dA0 = dp[0], dA1 = dp[1];
    i32x4 hA0 = hp0[0], hA1 = hp1[0], hA2 = hp2[0], hA3 = hp3[0];
    mp0 += 8; mp1 += 8; dp += 64; hp0 += 32; hp1 += 32; hp2 += 32; hp3 += 32;
    unsigned mB0, mB1; f32x4 dB0, dB1; i32x4 hB0, hB1, hB2, hB3;
    s16x8 pkA0, pkA1, pkB0, pkB1;

    #pragma unroll 1
    for (int c = 0; c < NCHS; c += 2) {
        LOADSET(B, (c + 1) < NCHS);
        GEN(mA0, dA0, dA1, sv0, dsum0, pkA0);
        GEN(mA1, dA0, dA1, sv1, dsum1, pkA1);
        MM8(pkA0, pkA1, hA0, hA1, hA2, hA3);
        LOADSET(A, (c + 2) < NCHS);
        GEN(mB0, dB0, dB1, sv0, dsum0, pkB0);
        GEN(mB1, dB0, dB1, sv1, dsum1, pkB1);
        MM8(pkB0, pkB1, hB0, hB1, hB2, hB3);
    }

#undef GEN
#undef LOADSET
#undef MM8

    // denominators: reduce the 4 k-groups within the wave
    float d2 = dsum0;
    d2 += __shfl_xor(d2, 16); d2 += __shfl_xor(d2, 32);
    if (kg == 0) dred[w][row] = d2;
    float d3 = dsum1;
    d3 += __shfl_xor(d3, 16); d3 += __shfl_xor(d3, 32);
    if (kg == 0) dred[w][16 + row] = d3;

    #pragma unroll
    for (int j = 0; j < 4; ++j) {
        cred[w][kg*4 + j][0*16 + row] = q00[j];
        cred[w][kg*4 + j][1*16 + row] = q01[j];
        cred[w][kg*4 + j][2*16 + row] = q02[j];
        cred[w][kg*4 + j][3*16 + row] = q03[j];
        cred[w][16 + kg*4 + j][0*16 + row] = q10[j];
        cred[w][16 + kg*4 + j][1*16 + row] = q11[j];
        cred[w][16 + kg*4 + j][2*16 + row] = q12[j];
        cred[w][16 + kg*4 + j][3*16 + row] = q13[j];
    }
    __syncthreads();

    // combine across 8 waves -> partials. thread t: row t>>4, f=(t&15)*4
    const int r  = t >> 4;
    const int f0 = (t & 15) * 4;
    float den = 0.f;
    #pragma unroll
    for (int ww = 0; ww < 8; ++ww) den += dred[ww][r];
    float4 o;
    float* op = (float*)&o;
    #pragma unroll
    for (int e = 0; e < 4; ++e) {
        float v = 0.f;
        #pragma unroll
        for (int ww = 0; ww < 8; ++ww) v += cred[ww][r][f0 + e];
        op[e] = v;
    }
    *reinterpret_cast<float4*>(&pacc[((size_t)jb * NN + i0 + r) * FD + f0]) = o;
    if (f0 == 0) pden[(size_t)jb * NN + i0 + r] = den;
}

// ---------------- kernel 3: merge j-halves, divide, ELU ----------------------
__global__ __launch_bounds__(256) void k_merge(const float* __restrict__ pacc,
        const float* __restrict__ pden, float* __restrict__ out)
{
    const int idx = blockIdx.x * 256 + threadIdx.x;   // one float4 per thread
    const int r  = idx >> 4;
    const int f0 = (idx & 15) * 4;
    const float den = pden[r] + pden[NN + r];
    const float4 a0 = *reinterpret_cast<const float4*>(&pacc[(size_t)r * FD + f0]);
    const float4 a1 = *reinterpret_cast<const float4*>(&pacc[(size_t)(NN + r) * FD + f0]);
    float4 o;
    float* op = (float*)&o;
    const float* p0 = (const float*)&a0;
    const float* p1 = (const float*)&a1;
    #pragma unroll
    for (int e = 0; e < 4; ++e) {
        float v = (p0[e] + p1[e]) / den;
        op[e] = (v > 0.f) ? v : expm1f(v);
    }
    *reinterpret_cast<float4*>(&out[(size_t)r * FD + f0]) = o;
}

extern "C" void kernel_launch(void* const* d_in, const int* in_sizes, int n_in,
                              void* d_out, int out_size, void* d_ws, size_t ws_size,
                              hipStream_t stream) {
    const float* x   = (const float*)d_in[0];
    const int*   adj = (const int*)d_in[1];
    const float* W   = (const float*)d_in[2];
    const float* a   = (const float*)d_in[3];
    float* out = (float*)d_out;

    unsigned* bmw = (unsigned*)d_ws;                         // 8 MB
    short* hT   = (short*)(bmw + NWORDS);                    // 1 MB
    float* src  = (float*)((char*)hT + (size_t)FD * NN * 2); // 32 KB
    float* dst  = src + NN;                                  // 32 KB
    float* pacc = dst + NN;                                  // 2 x 8192 x 64 = 4 MB
    float* pden = pacc + (size_t)JSPLIT * NN * FD;           // 64 KB

    k_compress<<<1024, 256, 0, stream>>>(adj, bmw);
    k_proj<<<NN / 32, 256, 0, stream>>>(x, W, a, hT, src, dst);
    k_attn<<<(NN / IT) * JSPLIT, 512, 0, stream>>>(bmw, hT, src, dst, pacc, pden);
    k_merge<<<NN * FD / 4 / 256, 256, 0, stream>>>(pacc, pden, out);
}

// Round 10
// 133.596 us; speedup vs baseline: 1.8959x; 1.0999x over previous
//
#include <hip/hip_runtime.h>
#include <hip/hip_bf16.h>
#include <cmath>

#define NN 8192
#define FIN 512
#define FD 64
#define IT 32            // rows per k_attn block
#define JCW 256          // j-chunk (8 waves x 32 k)
#define JSPLIT 2         // j-range split (512 blocks = 2/CU)
#define JRANGE (NN / JSPLIT)      // 4096
#define NCHS (JRANGE / JCW)       // 16 chunks
#define NWORDS (NN * (NN / 32))   // 2M bitmask words

typedef __attribute__((ext_vector_type(4))) float f32x4;
typedef __attribute__((ext_vector_type(4))) int   i32x4;
typedef __attribute__((ext_vector_type(8))) short s16x8;

static __device__ __forceinline__ s16x8 as_s16x8(i32x4 v) {
    s16x8 r; __builtin_memcpy(&r, &v, 16); return r;
}
static __device__ __forceinline__ short bf16bits(float f) {
    __hip_bfloat16 h = __float2bfloat16(f);
    short s; __builtin_memcpy(&s, &h, 2); return s;
}
// w = adj ? (s+d>0 ? e^s*e^d : e^{.2s}*e^{.2d}) : 0, from packed {Ed,Fd} bf16
static __device__ __forceinline__ float selw(unsigned pair, float ES, float FS,
                                             float iES, unsigned Ms, int bit) {
    const float Ed = __uint_as_float(pair << 16);
    const float Fd = __uint_as_float(pair & 0xFFFF0000u);
    const bool pos = Ed > iES;          // Ed > 1/Es  <=>  s+d > 0
    const float m1 = pos ? ES : FS;
    const float m2 = pos ? Ed : Fd;
    const float w  = m1 * m2;
    return ((Ms >> bit) & 1u) ? w : 0.0f;
}

// ---------------- kernel 0: adj (256MB int32) -> bitmask (8MB) ---------------
__global__ __launch_bounds__(256) void k_compress(const int* __restrict__ adj,
        unsigned* __restrict__ bm)
{
    const int t = threadIdx.x;
    const int l = t & 63;
    const int wv = t >> 6;
    const size_t fb0 = (size_t)blockIdx.x * 65536 + (size_t)wv * 16384;

    for (int r = 0; r < 32; ++r) {
        const size_t fb = fb0 + (size_t)r * 512;
        const int* p = adj + fb + l;
        const unsigned long long m0 = __ballot(__builtin_nontemporal_load(p +   0) > 0);
        const unsigned long long m1 = __ballot(__builtin_nontemporal_load(p +  64) > 0);
        const unsigned long long m2 = __ballot(__builtin_nontemporal_load(p + 128) > 0);
        const unsigned long long m3 = __ballot(__builtin_nontemporal_load(p + 192) > 0);
        const unsigned long long m4 = __ballot(__builtin_nontemporal_load(p + 256) > 0);
        const unsigned long long m5 = __ballot(__builtin_nontemporal_load(p + 320) > 0);
        const unsigned long long m6 = __ballot(__builtin_nontemporal_load(p + 384) > 0);
        const unsigned long long m7 = __ballot(__builtin_nontemporal_load(p + 448) > 0);
        if (l < 16) {
            const int i = l >> 1;
            const unsigned long long mm =
                (i < 4) ? ((i < 2) ? (i == 0 ? m0 : m1) : (i == 2 ? m2 : m3))
                        : ((i < 6) ? (i == 4 ? m4 : m5) : (i == 6 ? m6 : m7));
            const unsigned v = (l & 1) ? (unsigned)(mm >> 32) : (unsigned)mm;
            bm[fb / 32 + l] = v;
        }
    }
}

// ------- kernel 1: h = x@W -> hTf (MFMA-B-fragment order) ; row/col factors --
// hTf[gc][ft][lane][e] = h[gc*32 + (lane>>4)*8+e][ft*16 + (lane&15)] so a
// wave's B-frag load in k_attn is ONE contiguous 1KB global load.
__global__ __launch_bounds__(256) void k_proj(const float* __restrict__ x,
        const float* __restrict__ W, const float* __restrict__ a,
        short* __restrict__ hTf, float* __restrict__ es, float* __restrict__ fs,
        float* __restrict__ ies, unsigned* __restrict__ efbf)
{
    __shared__ short tl[32][64];
    const int t = threadIdx.x, lane = t & 63, wv = t >> 6;
    const int row0 = blockIdx.x * 32;
    const int r0 = wv * 8;
    const float a1 = a[lane], a2 = a[FD + lane];

    float acc[8] = {0.f,0.f,0.f,0.f,0.f,0.f,0.f,0.f};
    for (int k0 = 0; k0 < FIN; k0 += 4) {
        const float w0 = W[(k0+0)*FD + lane];
        const float w1 = W[(k0+1)*FD + lane];
        const float w2 = W[(k0+2)*FD + lane];
        const float w3 = W[(k0+3)*FD + lane];
        #pragma unroll
        for (int r = 0; r < 8; ++r) {
            const float4 xv = *reinterpret_cast<const float4*>(&x[(size_t)(row0+r0+r)*FIN + k0]);
            acc[r] = fmaf(xv.x, w0, fmaf(xv.y, w1, fmaf(xv.z, w2, fmaf(xv.w, w3, acc[r]))));
        }
    }
    #pragma unroll
    for (int r = 0; r < 8; ++r) {
        tl[r0 + r][lane] = bf16bits(acc[r]);
        float p1 = acc[r] * a1, p2 = acc[r] * a2;
        #pragma unroll
        for (int s = 32; s > 0; s >>= 1) { p1 += __shfl_xor(p1, s); p2 += __shfl_xor(p2, s); }
        if (lane == 0) {
            const int rr = row0 + r0 + r;
            const float Es = __expf(p1);
            es[rr]  = Es;
            fs[rr]  = __expf(0.2f * p1);
            ies[rr] = __expf(-p1);
            const unsigned edb = (unsigned)(unsigned short)bf16bits(__expf(p2));
            const unsigned fdb = (unsigned)(unsigned short)bf16bits(__expf(0.2f * p2));
            efbf[rr] = (fdb << 16) | edb;
        }
    }
    __syncthreads();
    // fragment-order write: thread t -> (ft = t>>6, lane l = t&63)
    const int ft = t >> 6, l = t & 63;
    alignas(16) short tmp[8];
    #pragma unroll
    for (int e = 0; e < 8; ++e) tmp[e] = tl[(l >> 4) * 8 + e][ft * 16 + (l & 15)];
    const size_t gc = blockIdx.x;     // one 32-col chunk per block
    *reinterpret_cast<int4*>(&hTf[gc * 2048 + (size_t)ft * 512 + (size_t)l * 8]) =
        *reinterpret_cast<int4*>(tmp);
}

// ---------------- kernel 2: barrier-free factored-GEN + MFMA PV --------------
// 512 blocks x 512 thr, block (ib,jb) = 32 rows x 4096 cols. Wave w = 32-col
// k-slice; GEN = packed {Ed,Fd} select (no exp/TRANS), A-frag straight from
// regs into MFMA; denominator via ones-B MFMA. Coalesced hTf B loads.
__global__ __launch_bounds__(512, 4) void k_attn(const unsigned* __restrict__ bm,
        const short* __restrict__ hTf, const float* __restrict__ es,
        const float* __restrict__ fs, const float* __restrict__ ies,
        const unsigned* __restrict__ efbf, float* __restrict__ pacc,
        float* __restrict__ pden)
{
    __shared__ float cred[8][32][68];   // [wave][row][f] (+4 pad)
    __shared__ float dred[8][32];

    const int t = threadIdx.x;
    const int jb = blockIdx.x & (JSPLIT - 1);
    const int i0 = (blockIdx.x >> 1) * IT;
    const int jbase = jb * JRANGE;
    const int w   = t >> 6;          // wave = k-slice 0..7
    const int l   = t & 63;
    const int row = l & 15;          // A row / C col
    const int kg  = l >> 4;          // k-group
    const int kb  = kg * 8;

    const float Es0 = es[i0 + row],      Fs0 = fs[i0 + row],      iS0 = ies[i0 + row];
    const float Es1 = es[i0 + 16 + row], Fs1 = fs[i0 + 16 + row], iS1 = ies[i0 + 16 + row];

    f32x4 qp00 = {0.f,0.f,0.f,0.f}, qp01 = {0.f,0.f,0.f,0.f};
    f32x4 qp02 = {0.f,0.f,0.f,0.f}, qp03 = {0.f,0.f,0.f,0.f};
    f32x4 qp10 = {0.f,0.f,0.f,0.f}, qp11 = {0.f,0.f,0.f,0.f};
    f32x4 qp12 = {0.f,0.f,0.f,0.f}, qp13 = {0.f,0.f,0.f,0.f};
    f32x4 qd0  = {0.f,0.f,0.f,0.f}, qd1  = {0.f,0.f,0.f,0.f};

    const s16x8 ONES = {0x3F80,0x3F80,0x3F80,0x3F80,0x3F80,0x3F80,0x3F80,0x3F80};

    const unsigned* mp0 = bm + (size_t)(i0 + row) * (NN / 32) + jbase / 32 + w;
    const unsigned* mp1 = bm + (size_t)(i0 + 16 + row) * (NN / 32) + jbase / 32 + w;
    const i32x4* ep = (const i32x4*)(efbf + jbase + w * 32 + kb);            // 2 x i32x4
    const i32x4* hp = (const i32x4*)(hTf + ((size_t)(jbase / 32) + w) * 2048 + (size_t)l * 8);

#define GEN(M,E0,E1,ES,FS,IS,PK) do { \
    const unsigned Ms = (M) >> kb; \
    (PK)[0] = bf16bits(selw((unsigned)(E0).x, ES, FS, IS, Ms, 0)); \
    (PK)[1] = bf16bits(selw((unsigned)(E0).y, ES, FS, IS, Ms, 1)); \
    (PK)[2] = bf16bits(selw((unsigned)(E0).z, ES, FS, IS, Ms, 2)); \
    (PK)[3] = bf16bits(selw((unsigned)(E0).w, ES, FS, IS, Ms, 3)); \
    (PK)[4] = bf16bits(selw((unsigned)(E1).x, ES, FS, IS, Ms, 4)); \
    (PK)[5] = bf16bits(selw((unsigned)(E1).y, ES, FS, IS, Ms, 5)); \
    (PK)[6] = bf16bits(selw((unsigned)(E1).z, ES, FS, IS, Ms, 6)); \
    (PK)[7] = bf16bits(selw((unsigned)(E1).w, ES, FS, IS, Ms, 7)); \
} while (0)

#define LOADSET(S, guard) do { if (guard) { \
    m##S##0 = mp0[0]; m##S##1 = mp1[0]; \
    e##S##0 = ep[0];  e##S##1 = ep[1]; \
    h##S##0 = hp[0]; h##S##1 = hp[64]; h##S##2 = hp[128]; h##S##3 = hp[192]; \
    mp0 += 8; mp1 += 8; ep += 64; hp += 2048; } \
} while (0)

#define MM(PK0,PK1,H0,H1,H2,H3) do { \
    qp00 = __builtin_amdgcn_mfma_f32_16x16x32_bf16((PK0), as_s16x8(H0), qp00, 0, 0, 0); \
    qp01 = __builtin_amdgcn_mfma_f32_16x16x32_bf16((PK0), as_s16x8(H1), qp01, 0, 0, 0); \
    qp02 = __builtin_amdgcn_mfma_f32_16x16x32_bf16((PK0), as_s16x8(H2), qp02, 0, 0, 0); \
    qp03 = __builtin_amdgcn_mfma_f32_16x16x32_bf16((PK0), as_s16x8(H3), qp03, 0, 0, 0); \
    qd0  = __builtin_amdgcn_mfma_f32_16x16x32_bf16((PK0), ONES,        qd0,  0, 0, 0); \
    qp10 = __builtin_amdgcn_mfma_f32_16x16x32_bf16((PK1), as_s16x8(H0), qp10, 0, 0, 0); \
    qp11 = __builtin_amdgcn_mfma_f32_16x16x32_bf16((PK1), as_s16x8(H1), qp11, 0, 0, 0); \
    qp12 = __builtin_amdgcn_mfma_f32_16x16x32_bf16((PK1), as_s16x8(H2), qp12, 0, 0, 0); \
    qp13 = __builtin_amdgcn_mfma_f32_16x16x32_bf16((PK1), as_s16x8(H3), qp13, 0, 0, 0); \
    qd1  = __builtin_amdgcn_mfma_f32_16x16x32_bf16((PK1), ONES,        qd1,  0, 0, 0); \
} while (0)

    // prefetch chunk 0 into set A
    unsigned mA0 = mp0[0], mA1 = mp1[0];
    i32x4 eA0 = ep[0], eA1 = ep[1];
    i32x4 hA0 = hp[0], hA1 = hp[64], hA2 = hp[128], hA3 = hp[192];
    mp0 += 8; mp1 += 8; ep += 64; hp += 2048;
    unsigned mB0, mB1; i32x4 eB0, eB1; i32x4 hB0, hB1, hB2, hB3;
    s16x8 pkA0, pkA1, pkB0, pkB1;

    #pragma unroll 1
    for (int c = 0; c < NCHS; c += 2) {
        LOADSET(B, (c + 1) < NCHS);
        GEN(mA0, eA0, eA1, Es0, Fs0, iS0, pkA0);
        GEN(mA1, eA0, eA1, Es1, Fs1, iS1, pkA1);
        MM(pkA0, pkA1, hA0, hA1, hA2, hA3);
        LOADSET(A, (c + 2) < NCHS);
        GEN(mB0, eB0, eB1, Es0, Fs0, iS0, pkB0);
        GEN(mB1, eB0, eB1, Es1, Fs1, iS1, pkB1);
        MM(pkB0, pkB1, hB0, hB1, hB2, hB3);
    }

#undef GEN
#undef LOADSET
#undef MM

    // denominators from ones-MFMA acc (all cols equal; col-0 lanes write)
    if (row == 0) {
        #pragma unroll
        for (int j = 0; j < 4; ++j) {
            dred[w][kg*4 + j]      = qd0[j];
            dred[w][16 + kg*4 + j] = qd1[j];
        }
    }
    #pragma unroll
    for (int j = 0; j < 4; ++j) {
        cred[w][kg*4 + j][0*16 + row] = qp00[j];
        cred[w][kg*4 + j][1*16 + row] = qp01[j];
        cred[w][kg*4 + j][2*16 + row] = qp02[j];
        cred[w][kg*4 + j][3*16 + row] = qp03[j];
        cred[w][16 + kg*4 + j][0*16 + row] = qp10[j];
        cred[w][16 + kg*4 + j][1*16 + row] = qp11[j];
        cred[w][16 + kg*4 + j][2*16 + row] = qp12[j];
        cred[w][16 + kg*4 + j][3*16 + row] = qp13[j];
    }
    __syncthreads();

    // combine across 8 waves -> partials. thread t: row t>>4, f=(t&15)*4
    const int r  = t >> 4;
    const int f0 = (t & 15) * 4;
    float den = 0.f;
    #pragma unroll
    for (int ww = 0; ww < 8; ++ww) den += dred[ww][r];
    float4 o;
    float* op = (float*)&o;
    #pragma unroll
    for (int e = 0; e < 4; ++e) {
        float v = 0.f;
        #pragma unroll
        for (int ww = 0; ww < 8; ++ww) v += cred[ww][r][f0 + e];
        op[e] = v;
    }
    *reinterpret_cast<float4*>(&pacc[((size_t)jb * NN + i0 + r) * FD + f0]) = o;
    if (f0 == 0) pden[(size_t)jb * NN + i0 + r] = den;
}

// ---------------- kernel 3: merge j-halves, divide, ELU ----------------------
__global__ __launch_bounds__(256) void k_merge(const float* __restrict__ pacc,
        const float* __restrict__ pden, float* __restrict__ out)
{
    const int idx = blockIdx.x * 256 + threadIdx.x;   // one float4 per thread
    const int r  = idx >> 4;
    const int f0 = (idx & 15) * 4;
    const float den = pden[r] + pden[NN + r];
    const float4 a0 = *reinterpret_cast<const float4*>(&pacc[(size_t)r * FD + f0]);
    const float4 a1 = *reinterpret_cast<const float4*>(&pacc[(size_t)(NN + r) * FD + f0]);
    float4 o;
    float* op = (float*)&o;
    const float* p0 = (const float*)&a0;
    const float* p1 = (const float*)&a1;
    #pragma unroll
    for (int e = 0; e < 4; ++e) {
        float v = (p0[e] + p1[e]) / den;
        op[e] = (v > 0.f) ? v : expm1f(v);
    }
    *reinterpret_cast<float4*>(&out[(size_t)r * FD + f0]) = o;
}

extern "C" void kernel_launch(void* const* d_in, const int* in_sizes, int n_in,
                              void* d_out, int out_size, void* d_ws, size_t ws_size,
                              hipStream_t stream) {
    const float* x   = (const float*)d_in[0];
    const int*   adj = (const int*)d_in[1];
    const float* W   = (const float*)d_in[2];
    const float* a   = (const float*)d_in[3];
    float* out = (float*)d_out;

    unsigned* bmw = (unsigned*)d_ws;                          // 8 MB
    short*    hTf = (short*)(bmw + NWORDS);                   // 1 MB
    float*    es  = (float*)(hTf + (size_t)FD * NN);          // 32 KB
    float*    fsb = es + NN;                                  // 32 KB
    float*    ies = fsb + NN;                                 // 32 KB
    unsigned* efb = (unsigned*)(ies + NN);                    // 32 KB
    float*    pacc = (float*)(efb + NN);                      // 4 MB
    float*    pden = pacc + (size_t)JSPLIT * NN * FD;         // 64 KB

    k_compress<<<1024, 256, 0, stream>>>(adj, bmw);
    k_proj<<<NN / 32, 256, 0, stream>>>(x, W, a, hTf, es, fsb, ies, efb);
    k_attn<<<(NN / IT) * JSPLIT, 512, 0, stream>>>(bmw, hTf, es, fsb, ies, efb, pacc, pden);
    k_merge<<<NN * FD / 4 / 256, 256, 0, stream>>>(pacc, pden, out);
}